// Round 4
// baseline (2986.615 us; speedup 1.0000x reference)
//
#include <hip/hip_runtime.h>

// Problem: B=4, S=2048, D=1024, H=16, head_dim=64.
// Inputs FP32 (per reference): batch[B,S,D], padding_mask[B,S] (int-ish, auto-detected),
// Wq,bq,Wk,bk,Wv,bv,Wo,bo, num_heads. Output FP32 [B,S,D] (reference output dtype = float32).
// ws layout (fp32): Qb[8M] | Kb[8M] | mask_i32[8192] = 64 MB + 32 KB.
// V is staged in d_out (32 MB exact; dead after attention, final GEMM overwrites).

#define Bb 4
#define Ss 2048
#define Dd 1024
#define Hh 16
#define HD 64
#define NEG_INF -1000000000.0f

__device__ __forceinline__ float4 load4(const float* p) { return *(const float4*)p; }

// ---------------- mask normalization (dtype auto-detect) ----------------
__global__ void normalize_mask(const unsigned char* __restrict__ raw, int* __restrict__ out, int n) {
    __shared__ int flags;
    if (threadIdx.x == 0) flags = 0;
    __syncthreads();
    int f = 0;
    for (int i = threadIdx.x; i < n; i += blockDim.x) {
        unsigned char c = raw[i];
        if ((i & 3) != 0 && c) f |= 1;        // nonzero off int32-lane -> not int32
        if ((i & 3) == 1 && c >= 2) f |= 2;   // exponent byte at %4==1 -> bf16
        if ((i & 3) == 3 && c >= 2) f |= 4;   // exponent byte at %4==3 -> f32
    }
    if (f) atomicOr(&flags, f);
    __syncthreads();
    int fl = flags;
    int layout;                 // 0=int32, 1=u8, 2=bf16, 3=f32
    if (!(fl & 1)) layout = 0;
    else if (fl & 2) layout = 2;
    else if (fl & 4) layout = 3;
    else layout = 1;
    for (int i = threadIdx.x; i < n; i += blockDim.x) {
        int v;
        if (layout == 0)      v = ((const int*)raw)[i];
        else if (layout == 1) v = raw[i];
        else if (layout == 2) v = ((const unsigned short*)raw)[i] != 0;
        else                  v = ((const unsigned*)raw)[i] != 0;
        out[i] = (v != 0) ? 1 : 0;
    }
}

// ---------------- tiled GEMM: C[M,N] = A[M,K] @ W[K,N] + bias (all fp32) ----------------
__global__ __launch_bounds__(256) void gemm_bias(
    const float* __restrict__ A, const float* __restrict__ W,
    const float* __restrict__ bias, float* __restrict__ C,
    int M, int N, int K)
{
    constexpr int BM = 64, BN = 64, BK = 16, PAD = 4;
    __shared__ float As[BK][BM + PAD];
    __shared__ float Bs[BK][BN + PAD];
    const int bm = blockIdx.y * BM, bn = blockIdx.x * BN;
    const int tid = threadIdx.x;
    const int tx = tid & 15, ty = tid >> 4;
    const int ar = tid >> 2, ac = (tid & 3) * 4;    // A tile: 64 rows x 16 k
    const int wk = tid >> 4, wn = (tid & 15) * 4;   // W tile: 16 k x 64 cols
    float acc[4][4] = {};
    for (int k0 = 0; k0 < K; k0 += BK) {
        float4 av = load4(A + (size_t)(bm + ar) * K + k0 + ac);
        float4 wv = load4(W + (size_t)(k0 + wk) * N + bn + wn);
        __syncthreads();                     // previous tile fully consumed
        As[ac + 0][ar] = av.x; As[ac + 1][ar] = av.y;
        As[ac + 2][ar] = av.z; As[ac + 3][ar] = av.w;
        *(float4*)&Bs[wk][wn] = wv;
        __syncthreads();
        #pragma unroll
        for (int kk = 0; kk < BK; ++kk) {
            float4 a4 = *(const float4*)&As[kk][ty << 2];
            float4 b4 = *(const float4*)&Bs[kk][tx << 2];
            float a_[4] = {a4.x, a4.y, a4.z, a4.w};
            float b_[4] = {b4.x, b4.y, b4.z, b4.w};
            #pragma unroll
            for (int i = 0; i < 4; i++)
                #pragma unroll
                for (int j = 0; j < 4; j++)
                    acc[i][j] = fmaf(a_[i], b_[j], acc[i][j]);
        }
    }
    #pragma unroll
    for (int i = 0; i < 4; i++) {
        int row = bm + (ty << 2) + i;
        #pragma unroll
        for (int j = 0; j < 4; j++) {
            int col = bn + (tx << 2) + j;
            C[(size_t)row * N + col] = acc[i][j] + bias[col];
        }
    }
}

// ---------------- flash attention (online softmax), no scale, mask=-1e9 ----------------
// grid: B*H*(S/32); block 256 = 4 waves; wave handles 8 q-rows, lane = key idx / head dim.
__global__ __launch_bounds__(256) void attention_kernel(
    const float* __restrict__ Q, const float* __restrict__ K,
    const float* __restrict__ V, const int* __restrict__ mask,
    float* __restrict__ ctx)
{
    constexpr int QT = 32, KT = 64, PAD = 4;
    __shared__ float Qs[QT][HD + PAD];
    __shared__ float Ks[KT][HD + PAD];
    __shared__ float Vs[KT][HD + PAD];
    __shared__ float Ps[4][8][KT + PAD];
    const int qt = blockIdx.x & 63;          // S/QT = 64
    const int bh = blockIdx.x >> 6;
    const int h = bh & 15, b = bh >> 4;
    const int tid = threadIdx.x, lane = tid & 63, wave = tid >> 6;
    const int q0 = qt * QT;
    const size_t rowbase = (size_t)b * Ss;

    // load Q tile (32 x 64) into LDS
    for (int idx = tid; idx < QT * HD / 4; idx += 256) {
        int r = idx >> 4, c4 = (idx & 15) * 4;
        *(float4*)&Qs[r][c4] = load4(Q + (rowbase + q0 + r) * Dd + h * HD + c4);
    }

    float m[8], l[8], acc[8];
    #pragma unroll
    for (int r = 0; r < 8; r++) { m[r] = -INFINITY; l[r] = 0.f; acc[r] = 0.f; }

    for (int kc = 0; kc < Ss / KT; kc++) {
        const int k0 = kc * KT;
        float4 kreg[4], vreg[4];
        int rr[4], cc[4];
        #pragma unroll
        for (int it = 0; it < 4; it++) {
            int idx = tid + it * 256;
            rr[it] = idx >> 4; cc[it] = (idx & 15) * 4;
            kreg[it] = load4(K + (rowbase + k0 + rr[it]) * Dd + h * HD + cc[it]);
            vreg[it] = load4(V + (rowbase + k0 + rr[it]) * Dd + h * HD + cc[it]);
        }
        const int mk = mask[b * Ss + k0 + lane];
        __syncthreads();                     // previous chunk fully consumed (also covers Q load, kc=0)
        #pragma unroll
        for (int it = 0; it < 4; it++) {
            *(float4*)&Ks[rr[it]][cc[it]] = kreg[it];
            *(float4*)&Vs[rr[it]][cc[it]] = vreg[it];
        }
        __syncthreads();

        // QK^T: lane = key, 8 q-rows per wave
        float s[8];
        #pragma unroll
        for (int r = 0; r < 8; r++) s[r] = 0.f;
        #pragma unroll 4
        for (int d4 = 0; d4 < HD; d4 += 4) {
            float4 kv = *(const float4*)&Ks[lane][d4];
            #pragma unroll
            for (int r = 0; r < 8; r++) {
                float4 qv = *(const float4*)&Qs[wave * 8 + r][d4];
                s[r] = fmaf(qv.x, kv.x, fmaf(qv.y, kv.y, fmaf(qv.z, kv.z, fmaf(qv.w, kv.w, s[r]))));
            }
        }

        // online softmax per row
        #pragma unroll
        for (int r = 0; r < 8; r++) {
            float sv = mk ? s[r] : NEG_INF;
            float mx = sv;
            #pragma unroll
            for (int off = 32; off > 0; off >>= 1) mx = fmaxf(mx, __shfl_xor(mx, off));
            float mnew = fmaxf(m[r], mx);
            float alpha = __expf(m[r] - mnew);      // m=-inf first chunk -> 0
            float p = __expf(sv - mnew);
            float ps = p;
            #pragma unroll
            for (int off = 32; off > 0; off >>= 1) ps += __shfl_xor(ps, off);
            l[r] = l[r] * alpha + ps;
            m[r] = mnew;
            acc[r] *= alpha;
            Ps[wave][r][lane] = p;
        }

        // P @ V: acc[r][d=lane] += sum_k p[r][k] * V[k][d]
        #pragma unroll 4
        for (int k4 = 0; k4 < KT; k4 += 4) {
            float v0 = Vs[k4 + 0][lane], v1 = Vs[k4 + 1][lane];
            float v2 = Vs[k4 + 2][lane], v3 = Vs[k4 + 3][lane];
            #pragma unroll
            for (int r = 0; r < 8; r++) {
                float4 p4 = *(const float4*)&Ps[wave][r][k4];
                acc[r] = fmaf(p4.x, v0, fmaf(p4.y, v1, fmaf(p4.z, v2, fmaf(p4.w, v3, acc[r]))));
            }
        }
        __syncthreads();
    }

    // epilogue: normalize, q-mask, store (ctx aliases Q: this block is sole owner of its slice)
    #pragma unroll
    for (int r = 0; r < 8; r++) {
        int q = q0 + wave * 8 + r;
        int qm = mask[b * Ss + q];
        float rl = l[r] > 0.f ? 1.f / l[r] : 0.f;
        float o = qm ? acc[r] * rl : 0.f;
        ctx[(rowbase + q) * Dd + h * HD + lane] = o;
    }
}

extern "C" void kernel_launch(void* const* d_in, const int* in_sizes, int n_in,
                              void* d_out, int out_size, void* d_ws, size_t ws_size,
                              hipStream_t stream) {
    const float* X  = (const float*)d_in[0];
    const unsigned char* mr = (const unsigned char*)d_in[1];
    const float* Wq = (const float*)d_in[2];
    const float* bq = (const float*)d_in[3];
    const float* Wk = (const float*)d_in[4];
    const float* bk = (const float*)d_in[5];
    const float* Wv = (const float*)d_in[6];
    const float* bv = (const float*)d_in[7];
    const float* Wo = (const float*)d_in[8];
    const float* bo = (const float*)d_in[9];
    float* out = (float*)d_out;

    const size_t SZ = (size_t)Bb * Ss * Dd;          // 8388608 elements
    float* Qb = (float*)d_ws;                        // 32 MB
    float* Kb = Qb + SZ;                             // 32 MB
    int* mnorm = (int*)(Kb + SZ);                    // 32 KB  (total ws use: ~64.03 MB)
    float* Vb = out;                                 // stage V in d_out (dead after attention)
    float* ctx = Qb;                                 // alias Q (safe, see attention epilogue)

    const int M = Bb * Ss, N = Dd, Kk = Dd;
    dim3 gg(N / 64, M / 64);                         // (16, 128)

    normalize_mask<<<1, 1024, 0, stream>>>(mr, mnorm, Bb * Ss);
    gemm_bias<<<gg, 256, 0, stream>>>(X, Wq, bq, Qb, M, N, Kk);
    gemm_bias<<<gg, 256, 0, stream>>>(X, Wk, bk, Kb, M, N, Kk);
    gemm_bias<<<gg, 256, 0, stream>>>(X, Wv, bv, Vb, M, N, Kk);
    attention_kernel<<<Bb * Hh * (Ss / 32), 256, 0, stream>>>(Qb, Kb, Vb, mnorm, ctx);
    gemm_bias<<<gg, 256, 0, stream>>>(ctx, Wo, bo, out, M, N, Kk);
}

// Round 5
// 888.342 us; speedup vs baseline: 3.3620x; 3.3620x over previous
//
#include <hip/hip_runtime.h>

// B=4, S=2048, D=1024, H=16, head_dim=64. Inputs fp32, output fp32.
// MFMA bf16 pipeline; fp32 accumulate. 2-pass split-bf16 for Q/K projections.
// ws (64MB): Xh[16] | Qb/ctx[16] | Kb[16] | Vt[16]  (Wo^T overlays Xh after its death)
// d_out (32MB) pre-final scratch: Xl[16] | Wqt[2] | Wkt[2] | Wvt[2] | mask_i32[32KB]

#define Bb 4
#define Ss 2048
#define Dd 1024
#define Hh 16
#define SZt 8388608
#define NEG_INF -1000000000.0f

typedef short bf16x8 __attribute__((ext_vector_type(8)));
typedef float f32x4 __attribute__((ext_vector_type(4)));
typedef unsigned short u16;

__device__ __forceinline__ float bf2f(u16 u) {
    return __builtin_bit_cast(float, ((unsigned)u) << 16);
}
__device__ __forceinline__ u16 f2bf(float f) {
    unsigned u = __builtin_bit_cast(unsigned, f);
    unsigned r = 0x7FFFu + ((u >> 16) & 1u);
    return (u16)((u + r) >> 16);
}
__device__ __forceinline__ bf16x8 ldfrag(const u16* p) {
    return __builtin_bit_cast(bf16x8, *(const uint4*)p);
}
__device__ __forceinline__ f32x4 mfma16(bf16x8 a, bf16x8 b, f32x4 c) {
    return __builtin_amdgcn_mfma_f32_16x16x32_bf16(a, b, c, 0, 0, 0);
}

// ---------------- mask normalization (dtype auto-detect; verified round 4) ----------------
__global__ void normalize_mask(const unsigned char* __restrict__ raw, int* __restrict__ out, int n) {
    __shared__ int flags;
    if (threadIdx.x == 0) flags = 0;
    __syncthreads();
    int f = 0;
    for (int i = threadIdx.x; i < n; i += blockDim.x) {
        unsigned char c = raw[i];
        if ((i & 3) != 0 && c) f |= 1;
        if ((i & 3) == 1 && c >= 2) f |= 2;
        if ((i & 3) == 3 && c >= 2) f |= 4;
    }
    if (f) atomicOr(&flags, f);
    __syncthreads();
    int fl = flags;
    int layout;                 // 0=int32, 1=u8, 2=bf16, 3=f32
    if (!(fl & 1)) layout = 0;
    else if (fl & 2) layout = 2;
    else if (fl & 4) layout = 3;
    else layout = 1;
    for (int i = threadIdx.x; i < n; i += blockDim.x) {
        int v;
        if (layout == 0)      v = ((const int*)raw)[i];
        else if (layout == 1) v = raw[i];
        else if (layout == 2) v = ((const u16*)raw)[i] != 0;
        else                  v = ((const unsigned*)raw)[i] != 0;
        out[i] = (v != 0) ? 1 : 0;
    }
}

// ---------------- X fp32 -> hi/lo bf16 split ----------------
__global__ __launch_bounds__(256) void convert_x(const float* __restrict__ X,
                                                 u16* __restrict__ Xh, u16* __restrict__ Xl) {
    size_t i = ((size_t)blockIdx.x * 256 + threadIdx.x) * 4;
    float4 v = *(const float4*)(X + i);
    u16 h0 = f2bf(v.x), h1 = f2bf(v.y), h2 = f2bf(v.z), h3 = f2bf(v.w);
    u16 l0 = f2bf(v.x - bf2f(h0)), l1 = f2bf(v.y - bf2f(h1));
    u16 l2 = f2bf(v.z - bf2f(h2)), l3 = f2bf(v.w - bf2f(h3));
    uint2 ph = { (unsigned)h0 | ((unsigned)h1 << 16), (unsigned)h2 | ((unsigned)h3 << 16) };
    uint2 pl = { (unsigned)l0 | ((unsigned)l1 << 16), (unsigned)l2 | ((unsigned)l3 << 16) };
    *(uint2*)(Xh + i) = ph;
    *(uint2*)(Xl + i) = pl;
}

// ---------------- W [K][N] fp32 -> Wt [N][K] bf16 (tiled transpose) ----------------
__global__ __launch_bounds__(256) void transpose_w(const float* __restrict__ W, u16* __restrict__ Wt) {
    __shared__ float t[32][33];
    const int tx = threadIdx.x, ty = threadIdx.y;
    const int n0 = blockIdx.x * 32, k0 = blockIdx.y * 32;
    #pragma unroll
    for (int i = 0; i < 4; i++)
        t[ty + i * 8][tx] = W[(size_t)(k0 + ty + i * 8) * Dd + n0 + tx];
    __syncthreads();
    #pragma unroll
    for (int i = 0; i < 4; i++)
        Wt[(size_t)(n0 + ty + i * 8) * Dd + k0 + tx] = f2bf(t[tx][ty + i * 8]);
}

// ---------------- MFMA GEMM, no LDS: C[8192,1024] = A[8192,1024] @ Wt^T + bias ----------------
// PASSES: 1 = Ah only; 2 = Ah + Al (split-fp32 precision).
// OUTMODE: 0 = bf16 [M][N]; 1 = bf16 V-transposed [b][h][d][s]; 2 = fp32 [M][N].
template <int PASSES, int OUTMODE>
__global__ __launch_bounds__(256) void gemm_mfma(
    const u16* __restrict__ Ah, const u16* __restrict__ Al,
    const u16* __restrict__ Wt, const float* __restrict__ bias,
    void* __restrict__ Cout)
{
    const int tid = threadIdx.x, lane = tid & 63, wave = tid >> 6;
    const int wm = wave >> 1, wn = wave & 1;
    const int bm = blockIdx.y * 128, bn = blockIdx.x * 128;
    const int l15 = lane & 15, lq = lane >> 4;
    f32x4 acc[4][4] = {};
    const u16 *ap[4], *alp[4], *bp[4];
    #pragma unroll
    for (int mt = 0; mt < 4; mt++) {
        size_t row = bm + wm * 64 + mt * 16 + l15;
        ap[mt] = Ah + row * Dd + lq * 8;
        if (PASSES == 2) alp[mt] = Al + row * Dd + lq * 8;
    }
    #pragma unroll
    for (int nt = 0; nt < 4; nt++) {
        size_t col = bn + wn * 64 + nt * 16 + l15;
        bp[nt] = Wt + col * Dd + lq * 8;
    }
    #pragma unroll 2
    for (int k = 0; k < Dd; k += 32) {
        bf16x8 b[4], a[4];
        #pragma unroll
        for (int nt = 0; nt < 4; nt++) b[nt] = ldfrag(bp[nt] + k);
        #pragma unroll
        for (int mt = 0; mt < 4; mt++) a[mt] = ldfrag(ap[mt] + k);
        #pragma unroll
        for (int mt = 0; mt < 4; mt++)
            #pragma unroll
            for (int nt = 0; nt < 4; nt++)
                acc[mt][nt] = mfma16(a[mt], b[nt], acc[mt][nt]);
        if (PASSES == 2) {
            bf16x8 al2[4];
            #pragma unroll
            for (int mt = 0; mt < 4; mt++) al2[mt] = ldfrag(alp[mt] + k);
            #pragma unroll
            for (int mt = 0; mt < 4; mt++)
                #pragma unroll
                for (int nt = 0; nt < 4; nt++)
                    acc[mt][nt] = mfma16(al2[mt], b[nt], acc[mt][nt]);
        }
    }
    float bv[4];
    #pragma unroll
    for (int nt = 0; nt < 4; nt++) bv[nt] = bias[bn + wn * 64 + nt * 16 + l15];
    #pragma unroll
    for (int mt = 0; mt < 4; mt++) {
        int r0 = bm + wm * 64 + mt * 16 + lq * 4;   // token row base (4 consecutive via reg)
        #pragma unroll
        for (int nt = 0; nt < 4; nt++) {
            int col = bn + wn * 64 + nt * 16 + l15;
            if (OUTMODE == 0) {
                #pragma unroll
                for (int rr = 0; rr < 4; rr++)
                    ((u16*)Cout)[(size_t)(r0 + rr) * Dd + col] = f2bf(acc[mt][nt][rr] + bv[nt]);
            } else if (OUTMODE == 1) {
                int hh = col >> 6, dd = col & 63, b_ = r0 >> 11, s0 = r0 & 2047;
                u16 e0 = f2bf(acc[mt][nt][0] + bv[nt]), e1 = f2bf(acc[mt][nt][1] + bv[nt]);
                u16 e2 = f2bf(acc[mt][nt][2] + bv[nt]), e3 = f2bf(acc[mt][nt][3] + bv[nt]);
                uint2 pk = { (unsigned)e0 | ((unsigned)e1 << 16), (unsigned)e2 | ((unsigned)e3 << 16) };
                *(uint2*)((u16*)Cout + (size_t)((b_ * Hh + hh) * 64 + dd) * Ss + s0) = pk;
            } else {
                #pragma unroll
                for (int rr = 0; rr < 4; rr++)
                    ((float*)Cout)[(size_t)(r0 + rr) * Dd + col] = acc[mt][nt][rr] + bv[nt];
            }
        }
    }
}

// ---------------- MFMA flash attention: no scale, mask=-1e9, barrier-free ----------------
// grid (S/64, H, B); 256 thr = 4 waves; wave owns 16 q-rows. K/V frags direct from global.
__global__ __launch_bounds__(256) void attn_mfma(
    u16* qctx, const u16* __restrict__ Kb, const u16* __restrict__ Vt,
    const int* __restrict__ mask)
{
    __shared__ u16 Ps[4][16][72];            // per-wave P tile, padded rows (144B = 36 words: 2-way max)
    const int tid = threadIdx.x, lane = tid & 63, wave = tid >> 6;
    const int l15 = lane & 15, lq = lane >> 4;
    const int q0 = blockIdx.x * 64, h = blockIdx.y, b = blockIdx.z;
    const int qrow = q0 + wave * 16;

    const u16* qp = qctx + (size_t)(b * Ss + qrow + l15) * Dd + h * 64 + lq * 8;
    const bf16x8 qf0 = ldfrag(qp), qf1 = ldfrag(qp + 32);

    float mi[4], li[4];
    f32x4 acc[4] = {};
    #pragma unroll
    for (int r = 0; r < 4; r++) { mi[r] = -INFINITY; li[r] = 0.f; }

    const u16* pp0 = &Ps[wave][l15][lq * 8];
    const u16* pp1 = &Ps[wave][l15][32 + lq * 8];
    const u16* vbase = Vt + (size_t)((b * Hh + h) * 64 + l15) * Ss + lq * 8;

    for (int k0 = 0; k0 < Ss; k0 += 64) {
        const u16* kbase = Kb + (size_t)(b * Ss + k0 + l15) * Dd + h * 64 + lq * 8;
        bf16x8 kf[4][2];
        int mk[4];
        #pragma unroll
        for (int nt = 0; nt < 4; nt++) {
            kf[nt][0] = ldfrag(kbase + (size_t)nt * 16 * Dd);
            kf[nt][1] = ldfrag(kbase + (size_t)nt * 16 * Dd + 32);
            mk[nt] = mask[b * Ss + k0 + nt * 16 + l15];
        }
        float sv[4][4];
        #pragma unroll
        for (int nt = 0; nt < 4; nt++) {
            f32x4 st = {};
            st = mfma16(qf0, kf[nt][0], st);
            st = mfma16(qf1, kf[nt][1], st);
            #pragma unroll
            for (int r = 0; r < 4; r++) sv[nt][r] = mk[nt] ? st[r] : NEG_INF;
        }
        // online softmax (rows = lq*4+r, spread over 16 lanes of this quad-group)
        float al[4], rs[4];
        #pragma unroll
        for (int r = 0; r < 4; r++) {
            float v = fmaxf(fmaxf(sv[0][r], sv[1][r]), fmaxf(sv[2][r], sv[3][r]));
            v = fmaxf(v, __shfl_xor(v, 1)); v = fmaxf(v, __shfl_xor(v, 2));
            v = fmaxf(v, __shfl_xor(v, 4)); v = fmaxf(v, __shfl_xor(v, 8));
            float mn = fmaxf(mi[r], v);
            al[r] = __expf(mi[r] - mn);      // first chunk: exp(-inf)=0
            mi[r] = mn;
        }
        #pragma unroll
        for (int nt = 0; nt < 4; nt++)
            #pragma unroll
            for (int r = 0; r < 4; r++) sv[nt][r] = __expf(sv[nt][r] - mi[r]);
        #pragma unroll
        for (int r = 0; r < 4; r++) {
            float s = sv[0][r] + sv[1][r] + sv[2][r] + sv[3][r];
            s += __shfl_xor(s, 1); s += __shfl_xor(s, 2);
            s += __shfl_xor(s, 4); s += __shfl_xor(s, 8);
            li[r] = li[r] * al[r] + s;
        }
        #pragma unroll
        for (int dt = 0; dt < 4; dt++)
            #pragma unroll
            for (int r = 0; r < 4; r++) acc[dt][r] *= al[r];
        // P: C-layout -> LDS -> A-layout (wave-private; no barrier, lgkmcnt only)
        #pragma unroll
        for (int nt = 0; nt < 4; nt++)
            #pragma unroll
            for (int r = 0; r < 4; r++)
                Ps[wave][lq * 4 + r][nt * 16 + l15] = f2bf(sv[nt][r]);
        bf16x8 pf0 = ldfrag(pp0), pf1 = ldfrag(pp1);
        #pragma unroll
        for (int dt = 0; dt < 4; dt++) {
            bf16x8 vf0 = ldfrag(vbase + (size_t)dt * 16 * Ss + k0);
            bf16x8 vf1 = ldfrag(vbase + (size_t)dt * 16 * Ss + k0 + 32);
            acc[dt] = mfma16(pf0, vf0, acc[dt]);
            acc[dt] = mfma16(pf1, vf1, acc[dt]);
        }
    }
    // epilogue: normalize, q-mask, bf16 store into qctx (aliases Q; block-disjoint slices)
    #pragma unroll
    for (int r = 0; r < 4; r++) {
        int q = q0 + wave * 16 + lq * 4 + r;
        int qm = mask[b * Ss + q];
        float rl = li[r] > 0.f ? 1.f / li[r] : 0.f;
        #pragma unroll
        for (int dt = 0; dt < 4; dt++) {
            float o = qm ? acc[dt][r] * rl : 0.f;
            qctx[(size_t)(b * Ss + q) * Dd + h * 64 + dt * 16 + l15] = f2bf(o);
        }
    }
}

extern "C" void kernel_launch(void* const* d_in, const int* in_sizes, int n_in,
                              void* d_out, int out_size, void* d_ws, size_t ws_size,
                              hipStream_t stream) {
    const float* X  = (const float*)d_in[0];
    const unsigned char* mr = (const unsigned char*)d_in[1];
    const float* Wq = (const float*)d_in[2];
    const float* bq = (const float*)d_in[3];
    const float* Wk = (const float*)d_in[4];
    const float* bk = (const float*)d_in[5];
    const float* Wv = (const float*)d_in[6];
    const float* bv = (const float*)d_in[7];
    const float* Wo = (const float*)d_in[8];
    const float* bo = (const float*)d_in[9];
    float* out = (float*)d_out;

    // ws (64 MB)
    u16* wsb = (u16*)d_ws;
    u16* Xh  = wsb;                // dies after V-gemm; Wo^T overlays
    u16* Qb  = wsb + (size_t)SZt;  // ctx aliases after attention
    u16* Kb  = wsb + 2 * (size_t)SZt;
    u16* Vt  = wsb + 3 * (size_t)SZt;
    u16* Wot = Xh;
    // d_out scratch (first 22 MB; all dead before final GEMM writes d_out)
    u16* ob  = (u16*)d_out;
    u16* Xl  = ob;
    u16* Wqt = ob + (size_t)SZt;
    u16* Wkt = Wqt + 1048576;
    u16* Wvt = Wkt + 1048576;
    int* mnorm = (int*)(Wvt + 1048576);

    dim3 tg(32, 32), tb(32, 8);
    dim3 gg(Dd / 128, (Bb * Ss) / 128);        // (8, 64)

    normalize_mask<<<1, 1024, 0, stream>>>(mr, mnorm, Bb * Ss);
    convert_x<<<SZt / 1024, 256, 0, stream>>>(X, Xh, Xl);
    transpose_w<<<tg, tb, 0, stream>>>(Wq, Wqt);
    transpose_w<<<tg, tb, 0, stream>>>(Wk, Wkt);
    transpose_w<<<tg, tb, 0, stream>>>(Wv, Wvt);
    gemm_mfma<2, 0><<<gg, 256, 0, stream>>>(Xh, Xl, Wqt, bq, Qb);
    gemm_mfma<2, 0><<<gg, 256, 0, stream>>>(Xh, Xl, Wkt, bk, Kb);
    gemm_mfma<1, 1><<<gg, 256, 0, stream>>>(Xh, nullptr, Wvt, bv, Vt);
    transpose_w<<<tg, tb, 0, stream>>>(Wo, Wot);               // Xh dead -> reuse
    attn_mfma<<<dim3(Ss / 64, Hh, Bb), 256, 0, stream>>>(Qb, Kb, Vt, mnorm);
    gemm_mfma<1, 2><<<gg, 256, 0, stream>>>(Qb, nullptr, Wot, bo, out);
}